// Round 7
// baseline (241.973 us; speedup 1.0000x reference)
//
#include <hip/hip_runtime.h>
#include <math.h>

// Problem constants: B=4, N=4096, C=2048, E=64, K=2
#define T_TOKENS 16384
#define C_DIM    2048
#define N_SEQ    4096
#define E_EXP    64
#define NSLICE   4        // split-K slices
#define KSLICE   512      // C_DIM / NSLICE
#define EPB      1024     // epilogue blocks
#define GN       131072   // gate elements per split part (64*2048)

typedef __attribute__((ext_vector_type(8))) short  short8;   // 8 bf16 = 4 VGPR
typedef __attribute__((ext_vector_type(4))) float  floatx4;

// ---- exact 3-way bf16 decomposition (truncation; residuals exact) ----------
__device__ __forceinline__ void splitv(float v, ushort& h, ushort& m, ushort& l) {
    unsigned u = __float_as_uint(v);
    h = (ushort)(u >> 16);
    float f1 = v - __uint_as_float(u & 0xffff0000u);       // exact
    unsigned u1 = __float_as_uint(f1);
    m = (ushort)(u1 >> 16);
    float f2 = f1 - __uint_as_float(u1 & 0xffff0000u);     // exact
    l = (ushort)(__float_as_uint(f2) >> 16);
}

__device__ __forceinline__ void splitpack8(const float4& a, const float4& b,
                                           short8& h, short8& m, short8& l) {
    ushort hh, mm, ll;
    splitv(a.x, hh, mm, ll); h[0] = hh; m[0] = mm; l[0] = ll;
    splitv(a.y, hh, mm, ll); h[1] = hh; m[1] = mm; l[1] = ll;
    splitv(a.z, hh, mm, ll); h[2] = hh; m[2] = mm; l[2] = ll;
    splitv(a.w, hh, mm, ll); h[3] = hh; m[3] = mm; l[3] = ll;
    splitv(b.x, hh, mm, ll); h[4] = hh; m[4] = mm; l[4] = ll;
    splitv(b.y, hh, mm, ll); h[5] = hh; m[5] = mm; l[5] = ll;
    splitv(b.z, hh, mm, ll); h[6] = hh; m[6] = mm; l[6] = ll;
    splitv(b.w, hh, mm, ll); h[7] = hh; m[7] = mm; l[7] = ll;
}

// RNE split for the one-time gate_w preprocessing
__device__ __forceinline__ void split3rne(float v, ushort& h, ushort& m, ushort& l) {
    unsigned u = __float_as_uint(v);
    unsigned r = (u + 0x7fffu + ((u >> 16) & 1u)) >> 16;
    h = (ushort)r;
    float e1 = v - __uint_as_float(r << 16);
    u = __float_as_uint(e1);
    r = (u + 0x7fffu + ((u >> 16) & 1u)) >> 16;
    m = (ushort)r;
    float e2 = e1 - __uint_as_float(r << 16);
    l = (ushort)(__float_as_uint(e2) >> 16);
}

// ---- shared ctx body: wave computes ctx[0..3][j] (bit-identical to R0) ----
__device__ __forceinline__ void ctx_body(
    int j, int lane, const float* __restrict__ rc,
    const float* __restrict__ ctx_w, float* __restrict__ ctx_out)
{
    const float4* wr = (const float4*)(ctx_w + (size_t)j * C_DIM);
    const float4* r0 = (const float4*)(rc);
    const float4* r1 = (const float4*)(rc + C_DIM);
    const float4* r2 = (const float4*)(rc + 2 * C_DIM);
    const float4* r3 = (const float4*)(rc + 3 * C_DIM);

    float s0 = 0.f, s1 = 0.f, s2 = 0.f, s3 = 0.f;
#pragma unroll
    for (int it = 0; it < 8; ++it) {
        float4 a  = wr[it * 64 + lane];
        float4 c0 = r0[it * 64 + lane];
        float4 c1 = r1[it * 64 + lane];
        float4 c2 = r2[it * 64 + lane];
        float4 c3 = r3[it * 64 + lane];
        s0 += a.x * c0.x + a.y * c0.y + a.z * c0.z + a.w * c0.w;
        s1 += a.x * c1.x + a.y * c1.y + a.z * c1.z + a.w * c1.w;
        s2 += a.x * c2.x + a.y * c2.y + a.z * c2.z + a.w * c2.w;
        s3 += a.x * c3.x + a.y * c3.y + a.z * c3.z + a.w * c3.w;
    }
#pragma unroll
    for (int off = 32; off; off >>= 1) {
        s0 += __shfl_xor(s0, off, 64);
        s1 += __shfl_xor(s1, off, 64);
        s2 += __shfl_xor(s2, off, 64);
        s3 += __shfl_xor(s3, off, 64);
    }
    if (lane == 0) {
        ctx_out[j]             = s0;
        ctx_out[C_DIM + j]     = s1;
        ctx_out[2 * C_DIM + j] = s2;
        ctx_out[3 * C_DIM + j] = s3;
    }
}

// ---------------------------------------------------------------------------
// Kernel 1: gsp split only (tiny; absorbs the post-poison L3 state first).
// ---------------------------------------------------------------------------
__global__ __launch_bounds__(256) void split_kernel(
    const float* __restrict__ gw, ushort* __restrict__ gsp)
{
    const int idx  = blockIdx.x * 256 + threadIdx.x;   // 0..131071
    const int j    = idx & 7;
    const int e    = (idx >> 3) & 63;
    const int koct = idx >> 9;
    float g = gw[(size_t)e * C_DIM + koct * 8 + j];
    ushort h, m, l;
    split3rne(g, h, m, l);
    gsp[idx]          = h;
    gsp[GN + idx]     = m;
    gsp[2 * GN + idx] = l;
}

// ---------------------------------------------------------------------------
// Kernel 2 (R7): full m97-style LDS staging for BOTH operands.
// R6 fixed B (ds_read path, -5us). R7 fixes A: the old per-lane A loads were
// row-scattered (16 lines/instr, 16B used per lane, HBM-cold x ~900cy) and
// R2-calibrated wave lifetimes (occ 21% => ~10k cyc/K-step) show those loads
// serialize. Now: per step each wave loads its 32x128B A-panel COALESCED
// (lane -> row l>>3, chunk l&7: 8 lanes per 128B line, 4 instrs), writes a
// wave-PRIVATE padded LDS tile [32][36] (no extra barrier; pad => free 2-way
// read conflicts; 16B-aligned), reads fragments via ds_read_b128 after the
// existing B-barrier. f32 values round-trip LDS unchanged; split + MFMA
// order identical => bit-identical P. LDS 60KB => 2 blocks/CU.
// Blocks 512..1023 = ctx (independent work).
// ---------------------------------------------------------------------------
__global__ __launch_bounds__(256, 2) void gemm_ctx_kernel(
    const float* __restrict__ x, const ushort* __restrict__ gsp,
    const float* __restrict__ rc, const float* __restrict__ ctx_w,
    float* __restrict__ ctx_out, float* __restrict__ P)
{
    __shared__ ushort Bs[2][3][2048];        // 24 KB (shared across waves)
    __shared__ float  As[4][2][32][36];      // 36 KB (wave-private tiles)

    if (blockIdx.x >= 128 * NSLICE) {
        const int lane = threadIdx.x & 63;
        const int j = (blockIdx.x - 128 * NSLICE) * 4 + (threadIdx.x >> 6); // 0..2047
        ctx_body(j, lane, rc, ctx_w, ctx_out);
        return;
    }

    const int tid   = threadIdx.x;
    const int wv    = tid >> 6;
    const int lane  = tid & 63;
    const int l15   = lane & 15;
    const int quad  = lane >> 4;
    const int l8r   = lane >> 3;            // 0..7: A-stage row-in-group
    const int l8c   = lane & 7;             // A-stage 16B chunk
    const int tile  = blockIdx.x & 127;     // 128 tiles x 128 tokens
    const int slice = blockIdx.x >> 7;      // 0..3
    const int tw    = tile * 128 + wv * 32; // wave token base
    const int cbase = slice * KSLICE;

    floatx4 acc[2][4];
#pragma unroll
    for (int s = 0; s < 2; ++s)
#pragma unroll
        for (int nt = 0; nt < 4; ++nt) acc[s][nt] = (floatx4){0.f, 0.f, 0.f, 0.f};

    // Coalesced A staging source: instr i covers rows i*8..i*8+7 of the
    // wave's 32-token strip; lane -> (row l>>3, col chunk (l&7)*4 floats).
    const float* xs_base = x + (size_t)(tw + l8r) * C_DIM + cbase + l8c * 4;

    // B staging source (R6 scheme): pre-swizzled source + swizzled read,
    // linear LDS dest (involution within each 4KB part).
    const int swsrc = (tid * 8) ^ (((tid >> 6) & 3) << 3);
    const size_t stepbase0 = (size_t)(cbase >> 3) * 512;   // slice koct base

    int roff[4];
#pragma unroll
    for (int nt = 0; nt < 4; ++nt)
        roff[nt] = quad * 512 + (((16 * nt + l15) ^ quad) << 3);

    const int NKS = KSLICE / 32;            // 16 K=32 steps

    // ---- prologue: issue B[0] and A[0] loads ----
    short8 bn0 = *(const short8*)(gsp + 0 * (size_t)GN + stepbase0 + swsrc);
    short8 bn1 = *(const short8*)(gsp + 1 * (size_t)GN + stepbase0 + swsrc);
    short8 bn2 = *(const short8*)(gsp + 2 * (size_t)GN + stepbase0 + swsrc);
    float4 la0 = *(const float4*)(xs_base + (size_t)0 * 8 * C_DIM);
    float4 la1 = *(const float4*)(xs_base + (size_t)1 * 8 * C_DIM);
    float4 la2 = *(const float4*)(xs_base + (size_t)2 * 8 * C_DIM);
    float4 la3 = *(const float4*)(xs_base + (size_t)3 * 8 * C_DIM);

#pragma unroll 2
    for (int ks = 0; ks < NKS; ++ks) {
        // --- commit staged B[ks] (shared) and A[ks] (wave-private) to LDS ---
        ushort* bw = &Bs[ks & 1][0][0];
        *(short8*)(bw + 0 * 2048 + tid * 8) = bn0;
        *(short8*)(bw + 1 * 2048 + tid * 8) = bn1;
        *(short8*)(bw + 2 * 2048 + tid * 8) = bn2;
        float* aw = &As[wv][ks & 1][0][0];
        *(float4*)(aw + (0 * 8 + l8r) * 36 + l8c * 4) = la0;
        *(float4*)(aw + (1 * 8 + l8r) * 36 + l8c * 4) = la1;
        *(float4*)(aw + (2 * 8 + l8r) * 36 + l8c * 4) = la2;
        *(float4*)(aw + (3 * 8 + l8r) * 36 + l8c * 4) = la3;

        // --- issue next-step B and A global loads (wrap on last; discarded) ---
        const int nk = (ks + 1 < NKS) ? (ks + 1) : 0;
        const size_t sb = stepbase0 + (size_t)nk * 2048;
        bn0 = *(const short8*)(gsp + 0 * (size_t)GN + sb + swsrc);
        bn1 = *(const short8*)(gsp + 1 * (size_t)GN + sb + swsrc);
        bn2 = *(const short8*)(gsp + 2 * (size_t)GN + sb + swsrc);
        la0 = *(const float4*)(xs_base + nk * 32 + (size_t)0 * 8 * C_DIM);
        la1 = *(const float4*)(xs_base + nk * 32 + (size_t)1 * 8 * C_DIM);
        la2 = *(const float4*)(xs_base + nk * 32 + (size_t)2 * 8 * C_DIM);
        la3 = *(const float4*)(xs_base + nk * 32 + (size_t)3 * 8 * C_DIM);

        __syncthreads();   // B[ks] (and A[ks]) LDS writes visible

        // --- read A fragments from LDS and split ---
        const float* ar = &As[wv][ks & 1][0][0];
        float4 a00 = *(const float4*)(ar + l15 * 36 + quad * 8);
        float4 a01 = *(const float4*)(ar + l15 * 36 + quad * 8 + 4);
        float4 a10 = *(const float4*)(ar + (16 + l15) * 36 + quad * 8);
        float4 a11 = *(const float4*)(ar + (16 + l15) * 36 + quad * 8 + 4);
        short8 ah0, am0, al0, ah1, am1, al1;
        splitpack8(a00, a01, ah0, am0, al0);
        splitpack8(a10, a11, ah1, am1, al1);

        // --- inner MFMA loop: B from LDS (swizzled read) ---
        const ushort* br = &Bs[ks & 1][0][0];
#pragma unroll
        for (int nt = 0; nt < 4; ++nt) {
            short8 bh = *(const short8*)(br + 0 * 2048 + roff[nt]);
            short8 bm = *(const short8*)(br + 1 * 2048 + roff[nt]);
            short8 bl = *(const short8*)(br + 2 * 2048 + roff[nt]);
            acc[0][nt] = __builtin_amdgcn_mfma_f32_16x16x32_bf16(ah0, bh, acc[0][nt], 0, 0, 0);
            acc[0][nt] = __builtin_amdgcn_mfma_f32_16x16x32_bf16(ah0, bm, acc[0][nt], 0, 0, 0);
            acc[0][nt] = __builtin_amdgcn_mfma_f32_16x16x32_bf16(am0, bh, acc[0][nt], 0, 0, 0);
            acc[0][nt] = __builtin_amdgcn_mfma_f32_16x16x32_bf16(ah0, bl, acc[0][nt], 0, 0, 0);
            acc[0][nt] = __builtin_amdgcn_mfma_f32_16x16x32_bf16(al0, bh, acc[0][nt], 0, 0, 0);
            acc[0][nt] = __builtin_amdgcn_mfma_f32_16x16x32_bf16(am0, bm, acc[0][nt], 0, 0, 0);
            acc[1][nt] = __builtin_amdgcn_mfma_f32_16x16x32_bf16(ah1, bh, acc[1][nt], 0, 0, 0);
            acc[1][nt] = __builtin_amdgcn_mfma_f32_16x16x32_bf16(ah1, bm, acc[1][nt], 0, 0, 0);
            acc[1][nt] = __builtin_amdgcn_mfma_f32_16x16x32_bf16(am1, bh, acc[1][nt], 0, 0, 0);
            acc[1][nt] = __builtin_amdgcn_mfma_f32_16x16x32_bf16(ah1, bl, acc[1][nt], 0, 0, 0);
            acc[1][nt] = __builtin_amdgcn_mfma_f32_16x16x32_bf16(al1, bh, acc[1][nt], 0, 0, 0);
            acc[1][nt] = __builtin_amdgcn_mfma_f32_16x16x32_bf16(am1, bm, acc[1][nt], 0, 0, 0);
        }
        // no end barrier: next iteration writes the OTHER buffer, whose last
        // readers finished before the barrier we just passed.
    }

    // C/D layout (R6-verified): col=l15 (expert 16nt+l15), row=quad*4+r
    float* Ps = P + ((size_t)slice * T_TOKENS + tw) * E_EXP;
#pragma unroll
    for (int s = 0; s < 2; ++s)
#pragma unroll
        for (int nt = 0; nt < 4; ++nt)
#pragma unroll
            for (int r = 0; r < 4; ++r)
                Ps[(size_t)(s * 16 + quad * 4 + r) * E_EXP + 16 * nt + l15] =
                    acc[s][nt][r];
}

// ---------------------------------------------------------------------------
// Kernel 3: cl[b][e] = dot(ctx[b,:], gate_w[e,:]) — 64 blocks, tiny.
// ---------------------------------------------------------------------------
__global__ __launch_bounds__(256) void cl_kernel(
    const float* __restrict__ gw, const float* __restrict__ ctx,
    float* __restrict__ cl)
{
    const int lane = threadIdx.x & 63;
    const int pk   = blockIdx.x * 4 + (threadIdx.x >> 6);  // 0..255
    const int b    = pk >> 6;
    const int e    = pk & 63;
    const float4* wr = (const float4*)(gw + (size_t)e * C_DIM);
    const float4* cr = (const float4*)(ctx + (size_t)b * C_DIM);
    float s = 0.f;
#pragma unroll
    for (int it = 0; it < 8; ++it) {
        float4 a = wr[it * 64 + lane];
        float4 c = cr[it * 64 + lane];
        s += a.x * c.x + a.y * c.y + a.z * c.z + a.w * c.w;
    }
#pragma unroll
    for (int off = 32; off; off >>= 1) s += __shfl_xor(s, off, 64);
    if (lane == 0) cl[pk] = s;
}

// ---------------------------------------------------------------------------
// Kernel 4 (epilogue, proven): deterministic slice sum + cl[b][e], fused
// top-2+sumexp butterfly, per-block LDS reduce -> bp[block][128].
// ---------------------------------------------------------------------------
__global__ __launch_bounds__(256) void epilogue_kernel(
    const float* __restrict__ P, const float* __restrict__ cl,
    float* __restrict__ out, float* __restrict__ bp)
{
    __shared__ float red[4][128];

    const int tid  = threadIdx.x;
    const int wv   = tid >> 6;
    const int lane = tid & 63;
    const int t0   = blockIdx.x * (T_TOKENS / EPB);     // 16 tokens
    const float clv = cl[(t0 >> 12) * 64 + lane];       // batch = t0/4096

    float imp_acc = 0.f, cnt_acc = 0.f;

    for (int tt = 0; tt < 4; ++tt) {
        const int t = t0 + wv * 4 + tt;
        float v = clv;
#pragma unroll
        for (int s = 0; s < NSLICE; ++s)
            v += P[((size_t)s * T_TOKENS + t) * E_EXP + lane];

        const float p = expf(v);
        float v1 = v;  int i1 = lane;
        float v2 = -INFINITY; int i2 = 0x7fffffff;
        float s = p;
#pragma unroll
        for (int off = 32; off; off >>= 1) {
            float ov1 = __shfl_xor(v1, off, 64);
            int   oi1 = __shfl_xor(i1, off, 64);
            float ov2 = __shfl_xor(v2, off, 64);
            int   oi2 = __shfl_xor(i2, off, 64);
            s += __shfl_xor(s, off, 64);
            const bool aw = (ov1 < v1) || (ov1 == v1 && i1 < oi1);
            const float lv = aw ? ov1 : v1;  const int li = aw ? oi1 : i1;
            const float wv2 = aw ? v2 : ov2; const int wi = aw ? i2 : oi2;
            if (!aw) { v1 = ov1; i1 = oi1; }
            const bool sw = (wv2 < lv) || (wv2 == lv && li < wi);
            v2 = sw ? lv : wv2; i2 = sw ? li : wi;
        }

        imp_acc += p / s;
        if (lane == i1 || lane == i2) cnt_acc += 1.f;

        if (lane == 0) {
            const float e2 = expf(v2 - v1);
            out[2 * t]     = (float)i1;
            out[2 * t + 1] = (float)i2;
            out[2 * T_TOKENS + 2 * t]     = 1.f / (1.f + e2);
            out[2 * T_TOKENS + 2 * t + 1] = e2 / (1.f + e2);
        }
    }

    red[wv][lane]      = imp_acc;
    red[wv][64 + lane] = cnt_acc;
    __syncthreads();
    if (tid < 128) {
        float s = red[0][tid] + red[1][tid] + red[2][tid] + red[3][tid];
        bp[(size_t)blockIdx.x * 128 + tid] = s;
    }
}

// ---------------------------------------------------------------------------
// Kernel 5: parallel bp reduce -> aux loss (proven)
// ---------------------------------------------------------------------------
__global__ __launch_bounds__(1024) void aux_kernel(
    const float* __restrict__ bp, int nb, float* __restrict__ out_aux)
{
    __shared__ float4 red[32][32];
    const int tid = threadIdx.x;
    const int c4  = tid & 31;
    const int grp = tid >> 5;

    const float4* bp4 = (const float4*)bp;
    float4 s = make_float4(0.f, 0.f, 0.f, 0.f);
    for (int r = grp; r < nb; r += 32) {
        float4 v = bp4[(size_t)r * 32 + c4];
        s.x += v.x; s.y += v.y; s.z += v.z; s.w += v.w;
    }
    red[grp][c4] = s;
    __syncthreads();

    if (tid < 32) {
        float4 t = make_float4(0.f, 0.f, 0.f, 0.f);
#pragma unroll
        for (int g = 0; g < 32; ++g) {
            float4 v = red[g][tid];
            t.x += v.x; t.y += v.y; t.z += v.z; t.w += v.w;
        }
        red[0][tid] = t;
    }
    __syncthreads();

    if (tid < 16) {
        float4 a = red[0][tid];
        float4 b = red[0][tid + 16];
        float v = a.x * b.x + a.y * b.y + a.z * b.z + a.w * b.w;
#pragma unroll
        for (int off = 8; off; off >>= 1) v += __shfl_xor(v, off, 64);
        if (tid == 0)
            out_aux[0] = (float)E_EXP * v / ((float)T_TOKENS * (float)T_TOKENS);
    }
}

// ---------------------------------------------------------------------------
// Fallback path kernels (ws too small): ctx-only + fused fp32 + aux
// ---------------------------------------------------------------------------
__global__ __launch_bounds__(256) void ctx_only_kernel(
    const float* __restrict__ rc, const float* __restrict__ ctx_w,
    float* __restrict__ ctx_out)
{
    const int lane = threadIdx.x & 63;
    const int j    = blockIdx.x * 4 + (threadIdx.x >> 6);
    ctx_body(j, lane, rc, ctx_w, ctx_out);
}

#define TM    64
#define FKC   64
#define FLSTR 68
__global__ __launch_bounds__(256) void router_fused_kernel(
    const float* __restrict__ x, const float* __restrict__ gate_w,
    const float* __restrict__ ctx, float* __restrict__ out,
    float* __restrict__ bp)
{
    __shared__ float xs[TM][FLSTR];
    __shared__ float gs[E_EXP][FLSTR];
    __shared__ float ls[TM][FLSTR];
    __shared__ float red[4][128];

    const int tid = threadIdx.x;
    const int eg  = tid & 15;
    const int tg  = tid >> 4;
    const int t0  = blockIdx.x * TM;
    const int b   = t0 / N_SEQ;
    const int sr  = tid >> 4;
    const int scg = tid & 15;
    const float* ctx_row = ctx + (size_t)b * C_DIM;

    float4 acc[4][4];
#pragma unroll
    for (int i = 0; i < 4; ++i)
#pragma unroll
        for (int j = 0; j < 4; ++j) acc[i][j] = make_float4(0.f, 0.f, 0.f, 0.f);

    float4 px[4], pg[4], pc;
    auto prefetch = [&](int kc) {
        const int c0 = kc * FKC + scg * 4;
        pc = *(const float4*)(ctx_row + c0);
#pragma unroll
        for (int i = 0; i < 4; ++i) {
            px[i] = *(const float4*)(x + (size_t)(t0 + sr + 16 * i) * C_DIM + c0);
            pg[i] = *(const float4*)(gate_w + (size_t)(sr + 16 * i) * C_DIM + c0);
        }
    };

    prefetch(0);
    const int NCHUNK = C_DIM / FKC;
    for (int kc = 0; kc < NCHUNK; ++kc) {
        __syncthreads();
#pragma unroll
        for (int i = 0; i < 4; ++i) {
            float4 v = px[i];
            v.x += pc.x; v.y += pc.y; v.z += pc.z; v.w += pc.w;
            *(float4*)&xs[sr + 16 * i][scg * 4] = v;
            *(float4*)&gs[sr + 16 * i][scg * 4] = pg[i];
        }
        __syncthreads();
        if (kc + 1 < NCHUNK) prefetch(kc + 1);
#pragma unroll
        for (int cc = 0; cc < FKC; cc += 4) {
            float4 xv[4], gv[4];
#pragma unroll
            for (int i = 0; i < 4; ++i) xv[i] = *(const float4*)&xs[tg + 16 * i][cc];
#pragma unroll
            for (int j = 0; j < 4; ++j) gv[j] = *(const float4*)&gs[eg + 16 * j][cc];
#pragma unroll
            for (int i = 0; i < 4; ++i)
#pragma unroll
                for (int j = 0; j < 4; ++j) {
                    acc[i][j].x = fmaf(xv[i].x, gv[j].x, acc[i][j].x);
                    acc[i][j].y = fmaf(xv[i].y, gv[j].y, acc[i][j].y);
                    acc[i][j].z = fmaf(xv[i].z, gv[j].z, acc[i][j].z);
                    acc[i][j].w = fmaf(xv[i].w, gv[j].w, acc[i][j].w);
                }
        }
    }

    __syncthreads();
#pragma unroll
    for (int i = 0; i < 4; ++i)
#pragma unroll
        for (int j = 0; j < 4; ++j)
            ls[tg + 16 * i][eg + 16 * j] =
                (acc[i][j].x + acc[i][j].y) + (acc[i][j].z + acc[i][j].w);
    __syncthreads();

    const int wv   = tid >> 6;
    const int lane = tid & 63;
    float imp_acc = 0.f, cnt_acc = 0.f;

    for (int tt = 0; tt < 16; ++tt) {
        const int tokL = wv * 16 + tt;
        const float v = ls[tokL][lane];
        const float p = expf(v);
        float v1 = v;  int i1 = lane;
        float v2 = -INFINITY; int i2 = 0x7fffffff;
        float s = p;
#pragma unroll
        for (int off = 32; off; off >>= 1) {
            float ov1 = __shfl_xor(v1, off, 64);
            int   oi1 = __shfl_xor(i1, off, 64);
            float ov2 = __shfl_xor(v2, off, 64);
            int   oi2 = __shfl_xor(i2, off, 64);
            s += __shfl_xor(s, off, 64);
            const bool aw = (ov1 < v1) || (ov1 == v1 && i1 < oi1);
            const float lv = aw ? ov1 : v1;  const int li = aw ? oi1 : i1;
            const float wv2 = aw ? v2 : ov2; const int wi = aw ? i2 : oi2;
            if (!aw) { v1 = ov1; i1 = oi1; }
            const bool sw = (wv2 < lv) || (wv2 == lv && li < wi);
            v2 = sw ? lv : wv2; i2 = sw ? li : wi;
        }
        imp_acc += p / s;
        if (lane == i1 || lane == i2) cnt_acc += 1.f;
        if (lane == 0) {
            const int t = t0 + tokL;
            const float e2 = expf(v2 - v1);
            out[2 * t]     = (float)i1;
            out[2 * t + 1] = (float)i2;
            out[2 * T_TOKENS + 2 * t]     = 1.f / (1.f + e2);
            out[2 * T_TOKENS + 2 * t + 1] = e2 / (1.f + e2);
        }
    }

    red[wv][lane]      = imp_acc;
    red[wv][64 + lane] = cnt_acc;
    __syncthreads();
    if (tid < 128) {
        float s = red[0][tid] + red[1][tid] + red[2][tid] + red[3][tid];
        bp[(size_t)blockIdx.x * 128 + tid] = s;
    }
}

extern "C" void kernel_launch(void* const* d_in, const int* in_sizes, int n_in,
                              void* d_out, int out_size, void* d_ws, size_t ws_size,
                              hipStream_t stream)
{
    (void)in_sizes; (void)n_in; (void)out_size;
    const float* x      = (const float*)d_in[0];
    const float* rc     = (const float*)d_in[1];
    const float* gate_w = (const float*)d_in[2];
    const float* ctx_w  = (const float*)d_in[3];
    float* out = (float*)d_out;

    float*  ctx = (float*)d_ws;                            // 8192 f
    float*  cl  = ctx + 8192;                              // 256 f
    float*  bp  = cl + 256;                                // EPB*128 f
    float*  P   = bp + (size_t)EPB * 128;                  // NSLICE*T*E f
    ushort* gsp = (ushort*)(P + (size_t)NSLICE * T_TOKENS * E_EXP); // 3*GN us

    const size_t need =
        (8192 + 256 + (size_t)EPB * 128 + (size_t)NSLICE * T_TOKENS * E_EXP)
            * sizeof(float)
        + (size_t)3 * GN * sizeof(ushort);

    if (ws_size >= need) {
        split_kernel<<<512, 256, 0, stream>>>(gate_w, gsp);
        gemm_ctx_kernel<<<128 * NSLICE + 512, 256, 0, stream>>>(
            x, gsp, rc, ctx_w, ctx, P);
        cl_kernel<<<64, 256, 0, stream>>>(gate_w, ctx, cl);
        epilogue_kernel<<<EPB, 256, 0, stream>>>(P, cl, out, bp);
        aux_kernel<<<1, 1024, 0, stream>>>(bp, EPB, out + 2 * 2 * T_TOKENS);
    } else {
        ctx_only_kernel<<<512, 256, 0, stream>>>(rc, ctx_w, ctx);
        router_fused_kernel<<<256, 256, 0, stream>>>(x, gate_w, ctx, out, bp);
        aux_kernel<<<1, 1024, 0, stream>>>(bp, 256, out + 2 * 2 * T_TOKENS);
    }
}